// Round 3
// baseline (119.292 us; speedup 1.0000x reference)
//
#include <hip/hip_runtime.h>
#include <hip/hip_bf16.h>
#include <math.h>

// GAT layer, V=8192, E=262144, D=128.
// out[i] = (S + sum_{distinct edges (i,j)} (exp(a_ij)-1)*hw[j]) / (V + sum (exp(a_ij)-1))
// a_ij = leakyrelu(s1[i]+s2[j], 0.2), s1=hw@att[:128], s2=hw@att[128:], S=colsum(hw).
//
// R2 -> R3: top-5 dispatches are all harness d_ws-poison fills (~43us, fixed).
// Our kernels (~75us): k_hw rebuilt for LDS-op amortization (float4 h reads,
// 2 rows/thread, 16 rows/block, grid 512 -> 2 blocks/CU); k_row dedup made
// branch-free (pre-pass) so gather loop pipelines; k_scatter int4-vectorized.

#define V 8192
#define E 262144
#define D 128
#define NEG_SLOPE 0.2f
#define CAP 96   // bucket capacity/row; max expected degree ~55 for E/V=32

#define FMA4(acc, hv, wv) { acc.x += (hv)*(wv).x; acc.y += (hv)*(wv).y; \
                            acc.z += (hv)*(wv).z; acc.w += (hv)*(wv).w; }

// ---------------- K1: hw = h @ W^T, fused s1/s2 + colsum S ------------------
// 512 blocks x 256 thr, 16 rows/block. LDS 76.8KB -> 2 blocks/CU, 2 waves/SIMD.
__global__ __launch_bounds__(256) void k_hw(const float* __restrict__ h,
                                            const float* __restrict__ W,
                                            const float* __restrict__ att,
                                            float* __restrict__ hw,
                                            float* __restrict__ s1,
                                            float* __restrict__ s2,
                                            float* __restrict__ S) {
    __shared__ float Wt[D * 132];      // W transposed, padded stride (16B-aligned rows)
    __shared__ float hs[16][D];        // h rows; reused as colsum scratch
    __shared__ float atts[2 * D];
    atts[threadIdx.x] = att[threadIdx.x];
    for (int e = threadIdx.x; e < D * D; e += 256) {
        int o = e >> 7, k = e & 127;
        Wt[k * 132 + o] = W[e];        // coalesced read; 8-way-conflict write (once/block)
    }
    int r0 = blockIdx.x * 16;
    for (int e = threadIdx.x; e < 16 * D; e += 256)
        hs[e >> 7][e & 127] = h[(r0 + (e >> 7)) * D + (e & 127)];
    __syncthreads();

    int c4 = (threadIdx.x & 31) * 4;   // 4-col group
    int rq = threadIdx.x >> 5;         // 0..7; this thread: rows rq and rq+8
    float4 acc0 = make_float4(0.f, 0.f, 0.f, 0.f);
    float4 acc1 = make_float4(0.f, 0.f, 0.f, 0.f);
    #pragma unroll 2
    for (int kq = 0; kq < D; kq += 4) {
        float4 ha = *(const float4*)&hs[rq][kq];        // broadcast b128
        float4 hb = *(const float4*)&hs[rq + 8][kq];
        float4 w0 = *(const float4*)&Wt[(kq + 0) * 132 + c4];
        float4 w1 = *(const float4*)&Wt[(kq + 1) * 132 + c4];
        float4 w2 = *(const float4*)&Wt[(kq + 2) * 132 + c4];
        float4 w3 = *(const float4*)&Wt[(kq + 3) * 132 + c4];
        FMA4(acc0, ha.x, w0); FMA4(acc0, ha.y, w1);
        FMA4(acc0, ha.z, w2); FMA4(acc0, ha.w, w3);
        FMA4(acc1, hb.x, w0); FMA4(acc1, hb.y, w1);
        FMA4(acc1, hb.z, w2); FMA4(acc1, hb.w, w3);
    }
    int rowa = r0 + rq, rowb = r0 + rq + 8;
    *(float4*)&hw[rowa * D + c4] = acc0;
    *(float4*)&hw[rowb * D + c4] = acc1;

    // fused s1/s2: reduce across the 32-lane column groups
    float p1a = acc0.x * atts[c4] + acc0.y * atts[c4 + 1] + acc0.z * atts[c4 + 2] + acc0.w * atts[c4 + 3];
    float p2a = acc0.x * atts[D + c4] + acc0.y * atts[D + c4 + 1] + acc0.z * atts[D + c4 + 2] + acc0.w * atts[D + c4 + 3];
    float p1b = acc1.x * atts[c4] + acc1.y * atts[c4 + 1] + acc1.z * atts[c4 + 2] + acc1.w * atts[c4 + 3];
    float p2b = acc1.x * atts[D + c4] + acc1.y * atts[D + c4 + 1] + acc1.z * atts[D + c4 + 2] + acc1.w * atts[D + c4 + 3];
    #pragma unroll
    for (int m = 16; m; m >>= 1) {
        p1a += __shfl_xor(p1a, m); p2a += __shfl_xor(p2a, m);
        p1b += __shfl_xor(p1b, m); p2b += __shfl_xor(p2b, m);
    }
    if ((threadIdx.x & 31) == 0) {
        s1[rowa] = p1a; s2[rowa] = p2a;
        s1[rowb] = p1b; s2[rowb] = p2b;
    }

    // fused colsum: per-thread 2-row sum -> LDS scratch -> 1 atomic/col/block
    __syncthreads();
    float* scr = &hs[0][0];
    scr[rq * D + c4 + 0] = acc0.x + acc1.x;
    scr[rq * D + c4 + 1] = acc0.y + acc1.y;
    scr[rq * D + c4 + 2] = acc0.z + acc1.z;
    scr[rq * D + c4 + 3] = acc0.w + acc1.w;
    __syncthreads();
    if (threadIdx.x < D) {
        float t = 0.f;
        #pragma unroll
        for (int r = 0; r < 8; ++r) t += scr[r * D + threadIdx.x];
        atomicAdd(&S[threadIdx.x], t);
    }
}

// ---------------- K2: scatter edges into per-src buckets (4 edges/thread) ---
__global__ __launch_bounds__(256) void k_scatter(const int* __restrict__ ei,
                                                 const float* __restrict__ s1,
                                                 const float* __restrict__ s2,
                                                 int* __restrict__ cnt,
                                                 int2* __restrict__ bucket) {
    int t = blockIdx.x * 256 + threadIdx.x;     // 65536 threads
    int4 sv = *(const int4*)&ei[4 * t];
    int4 dv = *(const int4*)&ei[E + 4 * t];
    const int* sp = &sv.x;
    const int* dp = &dv.x;
    #pragma unroll
    for (int j = 0; j < 4; ++j) {
        int src = sp[j], dst = dp[j];
        float a = s1[src] + s2[dst];
        a = a > 0.f ? a : NEG_SLOPE * a;
        float w = expf(a) - 1.f;
        int pos = atomicAdd(&cnt[src], 1);
        if (pos < CAP)
            bucket[src * CAP + pos] = make_int2(dst, __float_as_int(w));
    }
}

// ---------------- K3: per-row gather + dedup + epilogue (1 wave/row) --------
__global__ __launch_bounds__(256) void k_row(const int2* __restrict__ bucket,
                                             const int* __restrict__ cnt,
                                             const float* __restrict__ hw,
                                             const float* __restrict__ S,
                                             float* __restrict__ out) {
    int row = (blockIdx.x * 256 + threadIdx.x) >> 6;
    int lane = threadIdx.x & 63;
    int deg = cnt[row];
    if (deg > CAP) deg = CAP;
    const int2* b = bucket + row * CAP;
    int2 e0 = b[lane];
    int2 e1 = (lane < CAP - 64) ? b[64 + lane] : make_int2(-1, 0);
    int   d0 = (lane < deg)      ? e0.x : -1;
    float w0 = (lane < deg)      ? __int_as_float(e0.y) : 0.f;
    int   d1 = (64 + lane < deg) ? e1.x : -1;
    float w1 = (64 + lane < deg) ? __int_as_float(e1.y) : 0.f;
    int n0 = deg < 64 ? deg : 64;

    // branch-free dedup pre-pass: zero weight of entries whose dst appeared earlier
    bool dup0 = false, dup1 = false;
    for (int j = 0; j < n0; ++j) {
        int dj = __shfl(d0, j);
        dup0 |= (d0 == dj) & (lane > j);
        dup1 |= (d1 == dj);               // e1 indices (64+lane) always later
    }
    for (int j = 64; j < deg; ++j) {
        int dj = __shfl(d1, j - 64);
        dup1 |= (d1 == dj) & (lane > j - 64);
    }
    if (dup0) w0 = 0.f;
    if (dup1) w1 = 0.f;

    // straight-line gather loop (dup entries carry w=0)
    float2 acc = make_float2(0.f, 0.f);
    float dex = 0.f;                      // uniform across lanes
    for (int j = 0; j < n0; ++j) {
        int   dj = __shfl(d0, j);
        float wj = __shfl(w0, j);
        float2 hv = *(const float2*)&hw[dj * D + lane * 2];
        acc.x += wj * hv.x; acc.y += wj * hv.y;
        dex += wj;
    }
    for (int j = 64; j < deg; ++j) {
        int   dj = __shfl(d1, j - 64);
        float wj = __shfl(w1, j - 64);
        float2 hv = *(const float2*)&hw[dj * D + lane * 2];
        acc.x += wj * hv.x; acc.y += wj * hv.y;
        dex += wj;
    }

    float inv = 1.f / ((float)V + dex);
    float2 s = *(const float2*)&S[lane * 2];
    float2 o;
    o.x = (s.x + acc.x) * inv;
    o.y = (s.y + acc.y) * inv;
    *(float2*)&out[row * D + lane * 2] = o;
}

extern "C" void kernel_launch(void* const* d_in, const int* in_sizes, int n_in,
                              void* d_out, int out_size, void* d_ws, size_t ws_size,
                              hipStream_t stream) {
    const float* h   = (const float*)d_in[0];
    const int*   ei  = (const int*)d_in[1];
    const float* W   = (const float*)d_in[2];
    const float* att = (const float*)d_in[3];
    float* out = (float*)d_out;

    char* ws = (char*)d_ws;
    // workspace layout (bytes):
    //   hw     @ 0           4,194,304
    //   s1     @ 4,194,304      32,768
    //   s2     @ 4,227,072      32,768
    //   S      @ 4,259,840         512
    //   cnt    @ 4,260,352      32,768
    //   bucket @ 4,293,120   6,291,456  (8192 rows * 96 * 8B)
    float* hw  = (float*)(ws);
    float* s1  = (float*)(ws + 4194304);
    float* s2  = (float*)(ws + 4227072);
    float* S   = (float*)(ws + 4259840);
    int*   cnt = (int*)(ws + 4260352);
    int2*  bucket = (int2*)(ws + 4293120);

    // zero S + cnt (adjacent, one node)
    hipMemsetAsync(ws + 4259840, 0, 512 + 32768, stream);

    k_hw     <<<512,  256, 0, stream>>>(h, W, att, hw, s1, s2, S);
    k_scatter<<<256,  256, 0, stream>>>(ei, s1, s2, cnt, bucket);
    k_row    <<<2048, 256, 0, stream>>>(bucket, cnt, hw, S, out);
}